// Round 14
// baseline (376.352 us; speedup 1.0000x reference)
//
#include <hip/hip_runtime.h>
#include <hip/hip_bf16.h>

#define NN 100000   // nodes
#define NNP 100096  // NN padded to a FULL 128-row GEMM tile (782*128) — C-writes
                    // of the last m-tile must stay in-bounds (R13 bug: 100032 pad
                    // let the epilogue spill 64 KB into Wt -> dispatch-order race)
#define HH 4        // heads
#define DD 64       // dim per head
#define RR 2        // relations
#define EE 500000   // edges per relation
#define KK 256      // in_feat
#define HD 256      // H*D
#define HD2 512     // both relations' features per node
#define NEG_SLOPE 0.2f

typedef __attribute__((ext_vector_type(8))) short bfx8;
typedef __attribute__((ext_vector_type(4))) float f32x4;
typedef __attribute__((ext_vector_type(2))) __fp16 h2;

__device__ __forceinline__ ushort f2bf(float f){
    __hip_bfloat16 h = __float2bfloat16(f);
    return *(ushort*)&h;
}
__device__ __forceinline__ float bf2f(ushort u){
    return __uint_as_float(((unsigned)u) << 16);
}

// fused: zero cnt/cur/cursor + Wt[r*256+n][k] = bf16(W_src[r][k][n]) + wcatbT
__global__ void k_prep(const float* __restrict__ Ws, const float* __restrict__ Wd,
                       const float* __restrict__ al, const float* __restrict__ ar,
                       ushort* __restrict__ Wt, ushort* __restrict__ wcatbT,
                       unsigned* __restrict__ zbase){
    int gid = blockIdx.x*blockDim.x + threadIdx.x;
    // zero cnt, cur, cursor: 2*RR*NN + 8 words, strided over 131072 threads
    for (unsigned i = gid; i < 2u*RR*NN + 8u; i += (unsigned)RR*KK*HD)
        zbase[i] = 0u;
    if (gid >= RR*KK*HD) return;
    int r = gid >> 16;
    int idx = gid & 65535;
    int n = idx >> 8, k = idx & 255;
    Wt[gid] = f2bf(Ws[((size_t)r*KK + k)*HD + n]);
    if (gid < KK*16){
        int kw = gid >> 4, j = gid & 15;
        int rw = j >> 3, s = (j >> 2) & 1, h = j & 3;
        const float* w = (s ? Wd : Ws) + ((size_t)rw*KK + kw)*HD + h*DD;
        const float* a = (s ? ar : al) + (size_t)(rw*HH + h)*DD;
        float acc = 0.f;
        #pragma unroll 8
        for (int d=0; d<DD; ++d) acc += w[d]*a[d];
        wcatbT[(size_t)j*KK + kw] = f2bf(acc);
    }
}

__global__ void k_hist(const int* __restrict__ didx, unsigned* __restrict__ cnt){
    int gid = blockIdx.x*blockDim.x + threadIdx.x;
    if (gid >= RR*EE) return;
    int r = gid / EE;
    atomicAdd(&cnt[(size_t)r*NN + didx[gid]], 1u);
}

// segment base allocation: wave-scan + one cursor atomic per wave (order-free CSR)
__global__ void k_alloc(const unsigned* __restrict__ cnt, unsigned* __restrict__ base,
                        unsigned* __restrict__ cursor){
    int gid = blockIdx.x*blockDim.x + threadIdx.x;
    int lane = threadIdx.x & 63;
    unsigned c = (gid < RR*NN) ? cnt[gid] : 0u;
    unsigned x = c;
    #pragma unroll
    for (int off = 1; off < 64; off <<= 1){
        unsigned t = __shfl_up(x, off, 64);
        if (lane >= off) x += t;
    }
    unsigned wtotal = __shfl(x, 63, 64);
    unsigned wbase = 0u;
    if (lane == 63) wbase = atomicAdd(cursor, wtotal);
    wbase = __shfl(wbase, 63, 64);
    if (gid < RR*NN) base[gid] = wbase + x - c;
}

// scatter src + packed f16 el[4 heads] into dst-grouped slots
__global__ void k_scatter(const int* __restrict__ sidx, const int* __restrict__ didx,
                          const float* __restrict__ eall,
                          const unsigned* __restrict__ base, unsigned* __restrict__ cur,
                          int* __restrict__ esrc, uint2* __restrict__ epak){
    int gid = blockIdx.x*blockDim.x + threadIdx.x;
    if (gid >= RR*EE) return;
    int r = gid / EE;
    int s = sidx[gid];
    size_t rn = (size_t)r*NN + didx[gid];
    unsigned pos = base[rn] + atomicAdd(&cur[rn], 1u);
    esrc[pos] = s;
    float4 e4 = *(const float4*)(eall + (size_t)s*16 + r*8);
    h2 p0 = __builtin_amdgcn_cvt_pkrtz(e4.x, e4.y);
    h2 p1 = __builtin_amdgcn_cvt_pkrtz(e4.z, e4.w);
    uint2 u;
    u.x = *(unsigned*)&p0; u.y = *(unsigned*)&p1;
    epak[pos] = u;
}

// bf16 MFMA GEMM: fsall[M,512] = x[M,256] @ Wt^T (both relations), PLUS
// fused eall = x @ wcat by (n0==0, wn==0) waves from the same staged A-tiles.
// GRID IS N-MAJOR (grid.x = n-tiles): the 4 blocks sharing an A-tile dispatch
// adjacently -> A re-reads hit L2/L3 instead of re-fetching x 4x from HBM.
__global__ __launch_bounds__(256) void k_gemm(const float* __restrict__ Ax,
                                              const ushort* __restrict__ Bt,
                                              const ushort* __restrict__ wcatbT,
                                              ushort* __restrict__ C,
                                              float* __restrict__ eall){
    __shared__ ushort Ab[128*64];
    __shared__ ushort Bb[128*64];
    int tid = threadIdx.x;
    int w = tid >> 6, lane = tid & 63;
    int m0 = blockIdx.y * 128;
    int n0 = blockIdx.x * 128;
    int wm = w >> 1, wn = w & 1;      // 2x2 wave grid, 64x64 per wave
    int r16 = lane & 15, ksub = lane >> 4;
    f32x4 acc[4][4] = {};
    f32x4 acc_e[4] = {};
    bool doE = (n0 == 0) && (wn == 0);
    int srow  = lane >> 3;            // row within 8-row chunk
    int sunit = (lane & 7) ^ srow;    // pre-swizzled source 16B unit

    for (int k0 = 0; k0 < KK; k0 += 64){
        // stage A: f32 -> bf16, swizzled ds_write_b64
        #pragma unroll
        for (int i = 0; i < 8; ++i){
            int flat = tid + 256*i;           // 0..2047
            int row  = flat >> 4;             // 0..127
            int q    = flat & 15;             // float4 index within row
            int arw = m0 + row; if (arw >= NN) arw = NN-1;
            float4 v = *(const float4*)(Ax + (size_t)arw*KK + k0 + q*4);
            ushort4 b;
            b.x = f2bf(v.x); b.y = f2bf(v.y); b.z = f2bf(v.z); b.w = f2bf(v.w);
            int usw = (q >> 1) ^ (row & 7);
            *(ushort4*)((char*)Ab + row*128 + usw*16 + (q & 1)*8) = b;
        }
        // stage B: global_load_lds 16B, wave-uniform LDS base, pre-swizzled source
        #pragma unroll
        for (int i = 0; i < 4; ++i){
            int rowl = i*32 + w*8 + srow;     // n-index 0..127 (per-lane source row)
            const ushort* gb = Bt + (size_t)(n0 + rowl)*KK + k0 + sunit*8;
            __builtin_amdgcn_global_load_lds(
                (const __attribute__((address_space(1))) void*)gb,
                (__attribute__((address_space(3))) void*)(Bb + (i*32 + w*8)*64),
                16, 0, 0);
        }
        __syncthreads();
        #pragma unroll
        for (int kk = 0; kk < 64; kk += 32){
            bfx8 af[4], bfr[4];
            int ublk = ksub + (kk >> 3);          // logical 16B unit 0..7
            #pragma unroll
            for (int m = 0; m < 4; ++m){
                int row = wm*64 + m*16 + r16;
                af[m] = *(const bfx8*)(Ab + row*64 + ((ublk ^ (row & 7)) << 3));
            }
            #pragma unroll
            for (int n = 0; n < 4; ++n){
                int col = wn*64 + n*16 + r16;
                bfr[n] = *(const bfx8*)(Bb + col*64 + ((ublk ^ (col & 7)) << 3));
            }
            #pragma unroll
            for (int m = 0; m < 4; ++m)
                #pragma unroll
                for (int n = 0; n < 4; ++n)
                    acc[m][n] = __builtin_amdgcn_mfma_f32_16x16x32_bf16(
                                    af[m], bfr[n], acc[m][n], 0, 0, 0);
            if (doE){
                bfx8 be = *(const bfx8*)(wcatbT + (size_t)r16*KK + k0 + kk + ksub*8);
                #pragma unroll
                for (int m = 0; m < 4; ++m)
                    acc_e[m] = __builtin_amdgcn_mfma_f32_16x16x32_bf16(
                                    af[m], be, acc_e[m], 0, 0, 0);
            }
        }
        __syncthreads();
    }
    // epilogue: C/D layout col=lane&15, row=(lane>>4)*4+i ; store bf16, stride 512.
    // NNP is a multiple of 128 -> all rows in-bounds (no overflow into Wt).
    int cr = ksub, cc = r16;
    #pragma unroll
    for (int m = 0; m < 4; ++m){
        #pragma unroll
        for (int i = 0; i < 4; ++i){
            int row = m0 + wm*64 + m*16 + cr*4 + i;
            #pragma unroll
            for (int n = 0; n < 4; ++n)
                C[(size_t)row*HD2 + n0 + wn*64 + n*16 + cc] = f2bf(acc[m][n][i]);
        }
    }
    if (doE){
        #pragma unroll
        for (int m = 0; m < 4; ++m){
            #pragma unroll
            for (int i = 0; i < 4; ++i){
                int row = m0 + wm*64 + m*16 + cr*4 + i;
                if (row < NN) eall[(size_t)row*16 + cc] = acc_e[m][i];
            }
        }
    }
}

// one wave per node, both relations; feature-per-lane (4 f32/lane).
// MINIMAL-VGPR simple loop (occupancy is the lever for this latency-bound
// gather) + no-max softmax + epak f16 el stream + nt-store on out.
// Runs at the random-gather HBM ceiling (~2.85 TB/s).
__global__ __launch_bounds__(256) void k_agg(const unsigned* __restrict__ base,
                                             const unsigned* __restrict__ cnt,
                                             const int* __restrict__ esrc,
                                             const uint2* __restrict__ epak,
                                             const float* __restrict__ eall,
                                             const ushort* __restrict__ fsall,
                                             const float* __restrict__ bias,
                                             float* __restrict__ out){
    int w = threadIdx.x >> 6, lane = threadIdx.x & 63;
    int n = blockIdx.x*4 + w;
    int h = lane >> 4;
    float rx = 0.f, ry = 0.f, rz = 0.f, rw = 0.f;
    #pragma unroll
    for (int r = 0; r < RR; ++r){
        unsigned beg = base[(size_t)r*NN + n], num = cnt[(size_t)r*NN + n];
        float er = eall[(size_t)n*16 + r*8 + 4 + h];
        float den = 0.f;
        float ax = 0.f, ay = 0.f, az = 0.f, aw = 0.f;
        for (unsigned u = beg; u < beg + num; ++u){
            int s = esrc[u];
            uint2 ep = epak[u];
            unsigned wsel = (h & 2) ? ep.y : ep.x;
            ushort hv = (h & 1) ? (ushort)(wsel >> 16) : (ushort)wsel;
            __fp16 hf = *(__fp16*)&hv;
            float v = (float)hf + er;
            v = v > 0.f ? v : NEG_SLOPE*v;
            float p = __expf(v);
            ushort4 f = *(const ushort4*)(fsall + (size_t)s*HD2 + r*HD + lane*4);
            den += p;
            ax += p*bf2f(f.x); ay += p*bf2f(f.y);
            az += p*bf2f(f.z); aw += p*bf2f(f.w);
        }
        float inv = den > 0.f ? 1.f/den : 0.f;
        rx += ax*inv; ry += ay*inv;
        rz += az*inv; rw += aw*inv;
    }
    const float4 b0 = *(const float4*)(bias + lane*4);
    const float4 b1 = *(const float4*)(bias + HD + lane*4);
    f32x4 res;
    res[0] = rx + b0.x + b1.x; res[1] = ry + b0.y + b1.y;
    res[2] = rz + b0.z + b1.z; res[3] = rw + b0.w + b1.w;
    __builtin_nontemporal_store(res, (f32x4*)(out + (size_t)n*HD + lane*4));
}

extern "C" void kernel_launch(void* const* d_in, const int* in_sizes, int n_in,
                              void* d_out, int out_size, void* d_ws, size_t ws_size,
                              hipStream_t stream) {
    const float* x     = (const float*)d_in[0];
    const float* W_src = (const float*)d_in[1];
    const float* W_dst = (const float*)d_in[2];
    const float* al    = (const float*)d_in[3];
    const float* ar    = (const float*)d_in[4];
    const float* bias  = (const float*)d_in[5];
    const int*   sidx  = (const int*)d_in[6];
    const int*   didx  = (const int*)d_in[7];
    float* out = (float*)d_out;

    // workspace carve-up (~123.6 MB)
    ushort*   fsall  = (ushort*)d_ws;                        // NNP*512 bf16
    ushort*   Wt     = fsall + (size_t)NNP*HD2;              // 512*256 bf16
    ushort*   wcatbT = Wt + (size_t)RR*KK*HD;                // 16*256 bf16
    float*    eall   = (float*)(wcatbT + 16*KK);             // N*16 f32
    unsigned* cnt    = (unsigned*)(eall + (size_t)NN*16);    // R*N
    unsigned* cur    = cnt + (size_t)RR*NN;                  // R*N
    unsigned* cursor = cur + (size_t)RR*NN;                  // 8 (1 + pad)
    unsigned* base   = cursor + 8;                           // R*N
    int*      esrc   = (int*)(base + (size_t)RR*NN);         // R*E ints
    uint2*    epak   = (uint2*)(esrc + (size_t)RR*EE);       // R*E uint2

    k_prep<<<(RR*KK*HD + 255)/256, 256, 0, stream>>>(W_src, W_dst, al, ar, Wt, wcatbT, cnt);
    k_gemm<<<dim3(HD2/128, NNP/128), 256, 0, stream>>>(x, Wt, wcatbT, fsall, eall);

    k_hist<<<(RR*EE + 255)/256, 256, 0, stream>>>(didx, cnt);
    k_alloc<<<(RR*NN + 255)/256, 256, 0, stream>>>(cnt, base, cursor);
    k_scatter<<<(RR*EE + 255)/256, 256, 0, stream>>>(sidx, didx, eall, base, cur, esrc, epak);

    k_agg<<<NN/4, 256, 0, stream>>>(base, cnt, esrc, epak, eall, fsall, bias, out);
}

// Round 16
// 344.760 us; speedup vs baseline: 1.0916x; 1.0916x over previous
//
#include <hip/hip_runtime.h>
#include <hip/hip_bf16.h>

#define NN 100000   // nodes
#define NNP 100352  // 784 full 128-row GEMM tiles; C-writes stay in-bounds and
                    // 3136 blocks divide evenly over 8 XCDs
#define MT 784      // m-tiles
#define HH 4        // heads
#define DD 64       // dim per head
#define RR 2        // relations
#define EE 500000   // edges per relation
#define KK 256      // in_feat
#define HD 256      // H*D
#define HD2 512     // both relations' features per node
#define NEG_SLOPE 0.2f
// Workspace budget: R15 failed because 123,830,816 B exceeded ws_size (~118 MiB);
// R14's 123,568,672 B passed. This version: 123,030,816 B (base[] eliminated).

typedef __attribute__((ext_vector_type(8))) short bfx8;
typedef __attribute__((ext_vector_type(4))) float f32x4;
typedef __attribute__((ext_vector_type(2))) __fp16 h2;

__device__ __forceinline__ ushort f2bf(float f){
    __hip_bfloat16 h = __float2bfloat16(f);
    return *(ushort*)&h;
}
__device__ __forceinline__ float bf2f(ushort u){
    return __uint_as_float(((unsigned)u) << 16);
}

// fused: zero cnt+cursor + Wt[r*256+n][k] = bf16(W_src[r][k][n]) + wcatbT
__global__ void k_prep(const float* __restrict__ Ws, const float* __restrict__ Wd,
                       const float* __restrict__ al, const float* __restrict__ ar,
                       ushort* __restrict__ Wt, ushort* __restrict__ wcatbT,
                       unsigned* __restrict__ zbase){
    int gid = blockIdx.x*blockDim.x + threadIdx.x;
    // zero cnt + cursor: RR*NN + 8 words (cur is fully overwritten by k_alloc)
    for (unsigned i = gid; i < (unsigned)RR*NN + 8u; i += (unsigned)RR*KK*HD)
        zbase[i] = 0u;
    if (gid >= RR*KK*HD) return;
    int r = gid >> 16;
    int idx = gid & 65535;
    int n = idx >> 8, k = idx & 255;
    Wt[gid] = f2bf(Ws[((size_t)r*KK + k)*HD + n]);
    if (gid < KK*16){
        int kw = gid >> 4, j = gid & 15;
        int rw = j >> 3, s = (j >> 2) & 1, h = j & 3;
        const float* w = (s ? Wd : Ws) + ((size_t)rw*KK + kw)*HD + h*DD;
        const float* a = (s ? ar : al) + (size_t)(rw*HH + h)*DD;
        float acc = 0.f;
        #pragma unroll 8
        for (int d=0; d<DD; ++d) acc += w[d]*a[d];
        wcatbT[(size_t)j*KK + kw] = f2bf(acc);
    }
}

__global__ void k_hist(const int* __restrict__ didx, unsigned* __restrict__ cnt){
    int gid = blockIdx.x*blockDim.x + threadIdx.x;
    if (gid >= RR*EE) return;
    int r = gid / EE;
    atomicAdd(&cnt[(size_t)r*NN + didx[gid]], 1u);
}

// segment START allocation written INTO cur (base[] array eliminated):
// k_scatter bumps cur start->end; k_agg recovers beg = cur - cnt.
__global__ void k_alloc(const unsigned* __restrict__ cnt, unsigned* __restrict__ cur,
                        unsigned* __restrict__ cursor){
    int gid = blockIdx.x*blockDim.x + threadIdx.x;
    int lane = threadIdx.x & 63;
    unsigned c = (gid < RR*NN) ? cnt[gid] : 0u;
    unsigned x = c;
    #pragma unroll
    for (int off = 1; off < 64; off <<= 1){
        unsigned t = __shfl_up(x, off, 64);
        if (lane >= off) x += t;
    }
    unsigned wtotal = __shfl(x, 63, 64);
    unsigned wbase = 0u;
    if (lane == 63) wbase = atomicAdd(cursor, wtotal);
    wbase = __shfl(wbase, 63, 64);
    if (gid < RR*NN) cur[gid] = wbase + x - c;   // segment start
}

// scatter src + packed f16 el[4 heads] into dst-grouped slots
__global__ void k_scatter(const int* __restrict__ sidx, const int* __restrict__ didx,
                          const float* __restrict__ eall,
                          unsigned* __restrict__ cur,
                          int* __restrict__ esrc, uint2* __restrict__ epak){
    int gid = blockIdx.x*blockDim.x + threadIdx.x;
    if (gid >= RR*EE) return;
    int r = gid / EE;
    int s = sidx[gid];
    size_t rn = (size_t)r*NN + didx[gid];
    unsigned pos = atomicAdd(&cur[rn], 1u);     // cur marches start -> end
    esrc[pos] = s;
    float4 e4 = *(const float4*)(eall + (size_t)s*16 + r*8);
    h2 p0 = __builtin_amdgcn_cvt_pkrtz(e4.x, e4.y);
    h2 p1 = __builtin_amdgcn_cvt_pkrtz(e4.z, e4.w);
    uint2 u;
    u.x = *(unsigned*)&p0; u.y = *(unsigned*)&p1;
    epak[pos] = u;
}

// bf16 MFMA GEMM: fsall[M,512] = x[M,256] @ Wt^T (both relations), PLUS
// fused eall = x @ wcat by (n0==0, wn==0) waves from the same staged A-tiles.
// XCD-CHUNKED SWIZZLE (T1): contiguous m-chunk per XCD; the 4 n-tiles of one
// m-tile sit on consecutive slots of the SAME XCD -> A re-reads hit its L2.
__global__ __launch_bounds__(256) void k_gemm(const float* __restrict__ Ax,
                                              const ushort* __restrict__ Bt,
                                              const ushort* __restrict__ wcatbT,
                                              ushort* __restrict__ C,
                                              float* __restrict__ eall){
    __shared__ ushort Ab[128*64];
    __shared__ ushort Bb[128*64];
    int tid = threadIdx.x;
    int w = tid >> 6, lane = tid & 63;
    int bid = blockIdx.x;
    int xcd = bid & 7, slot = bid >> 3;          // 392 slots per XCD
    int m0 = (xcd*(MT/8) + (slot >> 2)) * 128;   // contiguous m-chunk per XCD
    int n0 = (slot & 3) * 128;                   // 4 n-tiles adjacent in slot order
    int wm = w >> 1, wn = w & 1;      // 2x2 wave grid, 64x64 per wave
    int r16 = lane & 15, ksub = lane >> 4;
    f32x4 acc[4][4] = {};
    f32x4 acc_e[4] = {};
    bool doE = (n0 == 0) && (wn == 0);
    int srow  = lane >> 3;            // row within 8-row chunk
    int sunit = (lane & 7) ^ srow;    // pre-swizzled source 16B unit

    for (int k0 = 0; k0 < KK; k0 += 64){
        // stage A: f32 -> bf16, swizzled ds_write_b64
        #pragma unroll
        for (int i = 0; i < 8; ++i){
            int flat = tid + 256*i;           // 0..2047
            int row  = flat >> 4;             // 0..127
            int q    = flat & 15;             // float4 index within row
            int arw = m0 + row; if (arw >= NN) arw = NN-1;
            float4 v = *(const float4*)(Ax + (size_t)arw*KK + k0 + q*4);
            ushort4 b;
            b.x = f2bf(v.x); b.y = f2bf(v.y); b.z = f2bf(v.z); b.w = f2bf(v.w);
            int usw = (q >> 1) ^ (row & 7);
            *(ushort4*)((char*)Ab + row*128 + usw*16 + (q & 1)*8) = b;
        }
        // stage B: global_load_lds 16B, wave-uniform LDS base, pre-swizzled source
        #pragma unroll
        for (int i = 0; i < 4; ++i){
            int rowl = i*32 + w*8 + srow;     // n-index 0..127 (per-lane source row)
            const ushort* gb = Bt + (size_t)(n0 + rowl)*KK + k0 + sunit*8;
            __builtin_amdgcn_global_load_lds(
                (const __attribute__((address_space(1))) void*)gb,
                (__attribute__((address_space(3))) void*)(Bb + (i*32 + w*8)*64),
                16, 0, 0);
        }
        __syncthreads();
        #pragma unroll
        for (int kk = 0; kk < 64; kk += 32){
            bfx8 af[4], bfr[4];
            int ublk = ksub + (kk >> 3);          // logical 16B unit 0..7
            #pragma unroll
            for (int m = 0; m < 4; ++m){
                int row = wm*64 + m*16 + r16;
                af[m] = *(const bfx8*)(Ab + row*64 + ((ublk ^ (row & 7)) << 3));
            }
            #pragma unroll
            for (int n = 0; n < 4; ++n){
                int col = wn*64 + n*16 + r16;
                bfr[n] = *(const bfx8*)(Bb + col*64 + ((ublk ^ (col & 7)) << 3));
            }
            #pragma unroll
            for (int m = 0; m < 4; ++m)
                #pragma unroll
                for (int n = 0; n < 4; ++n)
                    acc[m][n] = __builtin_amdgcn_mfma_f32_16x16x32_bf16(
                                    af[m], bfr[n], acc[m][n], 0, 0, 0);
            if (doE){
                bfx8 be = *(const bfx8*)(wcatbT + (size_t)r16*KK + k0 + kk + ksub*8);
                #pragma unroll
                for (int m = 0; m < 4; ++m)
                    acc_e[m] = __builtin_amdgcn_mfma_f32_16x16x32_bf16(
                                    af[m], be, acc_e[m], 0, 0, 0);
            }
        }
        __syncthreads();
    }
    // epilogue: C/D layout col=lane&15, row=(lane>>4)*4+i ; store bf16, stride 512.
    // NNP is a multiple of 128 -> all rows in-bounds.
    int cr = ksub, cc = r16;
    #pragma unroll
    for (int m = 0; m < 4; ++m){
        #pragma unroll
        for (int i = 0; i < 4; ++i){
            int row = m0 + wm*64 + m*16 + cr*4 + i;
            #pragma unroll
            for (int n = 0; n < 4; ++n)
                C[(size_t)row*HD2 + n0 + wn*64 + n*16 + cc] = f2bf(acc[m][n][i]);
        }
    }
    if (doE){
        #pragma unroll
        for (int m = 0; m < 4; ++m){
            #pragma unroll
            for (int i = 0; i < 4; ++i){
                int row = m0 + wm*64 + m*16 + cr*4 + i;
                if (row < NN) eall[(size_t)row*16 + cc] = acc_e[m][i];
            }
        }
    }
}

// one wave per node, both relations; feature-per-lane (4 f32/lane).
// MINIMAL-VGPR simple loop + no-max softmax + epak f16 el stream + nt-store.
// Segment bounds: end = cur[rn] (post-scatter), beg = end - cnt[rn].
__global__ __launch_bounds__(256) void k_agg(const unsigned* __restrict__ cur,
                                             const unsigned* __restrict__ cnt,
                                             const int* __restrict__ esrc,
                                             const uint2* __restrict__ epak,
                                             const float* __restrict__ eall,
                                             const ushort* __restrict__ fsall,
                                             const float* __restrict__ bias,
                                             float* __restrict__ out){
    int w = threadIdx.x >> 6, lane = threadIdx.x & 63;
    int n = blockIdx.x*4 + w;
    int h = lane >> 4;
    float rx = 0.f, ry = 0.f, rz = 0.f, rw = 0.f;
    #pragma unroll
    for (int r = 0; r < RR; ++r){
        unsigned num = cnt[(size_t)r*NN + n];
        unsigned beg = cur[(size_t)r*NN + n] - num;   // cur = end after scatter
        float er = eall[(size_t)n*16 + r*8 + 4 + h];
        float den = 0.f;
        float ax = 0.f, ay = 0.f, az = 0.f, aw = 0.f;
        for (unsigned u = beg; u < beg + num; ++u){
            int s = esrc[u];
            uint2 ep = epak[u];
            unsigned wsel = (h & 2) ? ep.y : ep.x;
            ushort hv = (h & 1) ? (ushort)(wsel >> 16) : (ushort)wsel;
            __fp16 hf = *(__fp16*)&hv;
            float v = (float)hf + er;
            v = v > 0.f ? v : NEG_SLOPE*v;
            float p = __expf(v);
            ushort4 f = *(const ushort4*)(fsall + (size_t)s*HD2 + r*HD + lane*4);
            den += p;
            ax += p*bf2f(f.x); ay += p*bf2f(f.y);
            az += p*bf2f(f.z); aw += p*bf2f(f.w);
        }
        float inv = den > 0.f ? 1.f/den : 0.f;
        rx += ax*inv; ry += ay*inv;
        rz += az*inv; rw += aw*inv;
    }
    const float4 b0 = *(const float4*)(bias + lane*4);
    const float4 b1 = *(const float4*)(bias + HD + lane*4);
    f32x4 res;
    res[0] = rx + b0.x + b1.x; res[1] = ry + b0.y + b1.y;
    res[2] = rz + b0.z + b1.z; res[3] = rw + b0.w + b1.w;
    __builtin_nontemporal_store(res, (f32x4*)(out + (size_t)n*HD + lane*4));
}

extern "C" void kernel_launch(void* const* d_in, const int* in_sizes, int n_in,
                              void* d_out, int out_size, void* d_ws, size_t ws_size,
                              hipStream_t stream) {
    const float* x     = (const float*)d_in[0];
    const float* W_src = (const float*)d_in[1];
    const float* W_dst = (const float*)d_in[2];
    const float* al    = (const float*)d_in[3];
    const float* ar    = (const float*)d_in[4];
    const float* bias  = (const float*)d_in[5];
    const int*   sidx  = (const int*)d_in[6];
    const int*   didx  = (const int*)d_in[7];
    float* out = (float*)d_out;

    // workspace carve-up: 123,030,816 B total (below R14's proven 123,568,672)
    ushort*   fsall  = (ushort*)d_ws;                        // NNP*512 bf16
    ushort*   Wt     = fsall + (size_t)NNP*HD2;              // 512*256 bf16
    ushort*   wcatbT = Wt + (size_t)RR*KK*HD;                // 16*256 bf16
    float*    eall   = (float*)(wcatbT + 16*KK);             // N*16 f32
    unsigned* cnt    = (unsigned*)(eall + (size_t)NN*16);    // R*N
    unsigned* cursor = cnt + (size_t)RR*NN;                  // 8 (1 + pad)
    unsigned* cur    = cursor + 8;                           // R*N (start->end)
    int*      esrc   = (int*)(cur + (size_t)RR*NN);          // R*E ints
    uint2*    epak   = (uint2*)(esrc + (size_t)RR*EE);       // R*E uint2

    k_prep<<<(RR*KK*HD + 255)/256, 256, 0, stream>>>(W_src, W_dst, al, ar, Wt, wcatbT, cnt);
    k_gemm<<<MT*4, 256, 0, stream>>>(x, Wt, wcatbT, fsall, eall);

    k_hist<<<(RR*EE + 255)/256, 256, 0, stream>>>(didx, cnt);
    k_alloc<<<(RR*NN + 255)/256, 256, 0, stream>>>(cnt, cur, cursor);
    k_scatter<<<(RR*EE + 255)/256, 256, 0, stream>>>(sidx, didx, eall, cur, esrc, epak);

    k_agg<<<NN/4, 256, 0, stream>>>(cur, cnt, esrc, epak, eall, fsall, bias, out);
}

// Round 17
// 317.728 us; speedup vs baseline: 1.1845x; 1.0851x over previous
//
#include <hip/hip_runtime.h>
#include <hip/hip_bf16.h>

#define NN 100000   // nodes
#define NNP 100352  // 784 full 128-row GEMM tiles; C-writes stay in-bounds and
                    // 3136 blocks divide evenly over 8 XCDs
#define MT 784      // m-tiles
#define HH 4        // heads
#define DD 64       // dim per head
#define RR 2        // relations
#define EE 500000   // edges per relation
#define KK 256      // in_feat
#define HD 256      // H*D
#define HD2 512     // both relations' features per node
#define NEG_SLOPE 0.2f
// Workspace: 123,030,816 B (R15 failed at 123.83 MB; R14/R16 proven safe below that)

typedef __attribute__((ext_vector_type(8))) short bfx8;
typedef __attribute__((ext_vector_type(4))) float f32x4;
typedef __attribute__((ext_vector_type(2))) __fp16 h2;

__device__ __forceinline__ ushort f2bf(float f){
    __hip_bfloat16 h = __float2bfloat16(f);
    return *(ushort*)&h;
}
__device__ __forceinline__ float bf2f(ushort u){
    return __uint_as_float(((unsigned)u) << 16);
}

// fused: zero cnt+cursor + Wt[r*256+n][k] = bf16(W_src[r][k][n]) + wcatbT
__global__ void k_prep(const float* __restrict__ Ws, const float* __restrict__ Wd,
                       const float* __restrict__ al, const float* __restrict__ ar,
                       ushort* __restrict__ Wt, ushort* __restrict__ wcatbT,
                       unsigned* __restrict__ zbase){
    int gid = blockIdx.x*blockDim.x + threadIdx.x;
    // zero cnt + cursor: RR*NN + 8 words (cur is fully overwritten by k_alloc)
    for (unsigned i = gid; i < (unsigned)RR*NN + 8u; i += (unsigned)RR*KK*HD)
        zbase[i] = 0u;
    if (gid >= RR*KK*HD) return;
    int r = gid >> 16;
    int idx = gid & 65535;
    int n = idx >> 8, k = idx & 255;
    Wt[gid] = f2bf(Ws[((size_t)r*KK + k)*HD + n]);
    if (gid < KK*16){
        int kw = gid >> 4, j = gid & 15;
        int rw = j >> 3, s = (j >> 2) & 1, h = j & 3;
        const float* w = (s ? Wd : Ws) + ((size_t)rw*KK + kw)*HD + h*DD;
        const float* a = (s ? ar : al) + (size_t)(rw*HH + h)*DD;
        float acc = 0.f;
        #pragma unroll 8
        for (int d=0; d<DD; ++d) acc += w[d]*a[d];
        wcatbT[(size_t)j*KK + kw] = f2bf(acc);
    }
}

// segment START allocation written INTO cur (base[] eliminated):
// k_scatter bumps cur start->end; k_agg recovers beg = cur - cnt.
__global__ void k_alloc(const unsigned* __restrict__ cnt, unsigned* __restrict__ cur,
                        unsigned* __restrict__ cursor){
    int gid = blockIdx.x*blockDim.x + threadIdx.x;
    int lane = threadIdx.x & 63;
    unsigned c = (gid < RR*NN) ? cnt[gid] : 0u;
    unsigned x = c;
    #pragma unroll
    for (int off = 1; off < 64; off <<= 1){
        unsigned t = __shfl_up(x, off, 64);
        if (lane >= off) x += t;
    }
    unsigned wtotal = __shfl(x, 63, 64);
    unsigned wbase = 0u;
    if (lane == 63) wbase = atomicAdd(cursor, wtotal);
    wbase = __shfl(wbase, 63, 64);
    if (gid < RR*NN) cur[gid] = wbase + x - c;   // segment start
}

// scatter src + packed f16 el[4 heads] into dst-grouped slots
__global__ void k_scatter(const int* __restrict__ sidx, const int* __restrict__ didx,
                          const float* __restrict__ eall,
                          unsigned* __restrict__ cur,
                          int* __restrict__ esrc, uint2* __restrict__ epak){
    int gid = blockIdx.x*blockDim.x + threadIdx.x;
    if (gid >= RR*EE) return;
    int r = gid / EE;
    int s = sidx[gid];
    size_t rn = (size_t)r*NN + didx[gid];
    unsigned pos = atomicAdd(&cur[rn], 1u);     // cur marches start -> end
    esrc[pos] = s;
    float4 e4 = *(const float4*)(eall + (size_t)s*16 + r*8);
    h2 p0 = __builtin_amdgcn_cvt_pkrtz(e4.x, e4.y);
    h2 p1 = __builtin_amdgcn_cvt_pkrtz(e4.z, e4.w);
    uint2 u;
    u.x = *(unsigned*)&p0; u.y = *(unsigned*)&p1;
    epak[pos] = u;
}

// bf16 MFMA GEMM: fsall[M,512] = x[M,256] @ Wt^T (both relations), PLUS
// fused eall = x @ wcat (n0==0, wn==0 waves, same staged A-tiles), PLUS
// fused dst-HISTOGRAM prologue (independent work; cnt zeroed by k_prep, read
// by k_alloc after this kernel -> race-free; atomics complete under MFMA slack).
// XCD-CHUNKED SWIZZLE (T1): contiguous m-chunk per XCD; 4 n-tiles of one
// m-tile on consecutive slots of the SAME XCD -> A re-reads hit its L2.
__global__ __launch_bounds__(256) void k_gemm(const float* __restrict__ Ax,
                                              const ushort* __restrict__ Bt,
                                              const ushort* __restrict__ wcatbT,
                                              const int* __restrict__ didx,
                                              unsigned* __restrict__ cnt,
                                              ushort* __restrict__ C,
                                              float* __restrict__ eall){
    __shared__ ushort Ab[128*64];
    __shared__ ushort Bb[128*64];
    int tid = threadIdx.x;
    int w = tid >> 6, lane = tid & 63;
    int bid = blockIdx.x;
    // fused histogram: grid-stride over all edges (MT*4*256 = 802816 threads)
    for (unsigned e = (unsigned)bid*256 + tid; e < (unsigned)RR*EE; e += (unsigned)MT*4*256){
        unsigned r = e / EE;
        atomicAdd(&cnt[(size_t)r*NN + didx[e]], 1u);
    }
    int xcd = bid & 7, slot = bid >> 3;          // 392 slots per XCD
    int m0 = (xcd*(MT/8) + (slot >> 2)) * 128;   // contiguous m-chunk per XCD
    int n0 = (slot & 3) * 128;                   // 4 n-tiles adjacent in slot order
    int wm = w >> 1, wn = w & 1;      // 2x2 wave grid, 64x64 per wave
    int r16 = lane & 15, ksub = lane >> 4;
    f32x4 acc[4][4] = {};
    f32x4 acc_e[4] = {};
    bool doE = (n0 == 0) && (wn == 0);
    int srow  = lane >> 3;            // row within 8-row chunk
    int sunit = (lane & 7) ^ srow;    // pre-swizzled source 16B unit

    for (int k0 = 0; k0 < KK; k0 += 64){
        // stage A: f32 -> bf16, swizzled ds_write_b64
        #pragma unroll
        for (int i = 0; i < 8; ++i){
            int flat = tid + 256*i;           // 0..2047
            int row  = flat >> 4;             // 0..127
            int q    = flat & 15;             // float4 index within row
            int arw = m0 + row; if (arw >= NN) arw = NN-1;
            float4 v = *(const float4*)(Ax + (size_t)arw*KK + k0 + q*4);
            ushort4 b;
            b.x = f2bf(v.x); b.y = f2bf(v.y); b.z = f2bf(v.z); b.w = f2bf(v.w);
            int usw = (q >> 1) ^ (row & 7);
            *(ushort4*)((char*)Ab + row*128 + usw*16 + (q & 1)*8) = b;
        }
        // stage B: global_load_lds 16B, wave-uniform LDS base, pre-swizzled source
        #pragma unroll
        for (int i = 0; i < 4; ++i){
            int rowl = i*32 + w*8 + srow;     // n-index 0..127 (per-lane source row)
            const ushort* gb = Bt + (size_t)(n0 + rowl)*KK + k0 + sunit*8;
            __builtin_amdgcn_global_load_lds(
                (const __attribute__((address_space(1))) void*)gb,
                (__attribute__((address_space(3))) void*)(Bb + (i*32 + w*8)*64),
                16, 0, 0);
        }
        __syncthreads();
        #pragma unroll
        for (int kk = 0; kk < 64; kk += 32){
            bfx8 af[4], bfr[4];
            int ublk = ksub + (kk >> 3);          // logical 16B unit 0..7
            #pragma unroll
            for (int m = 0; m < 4; ++m){
                int row = wm*64 + m*16 + r16;
                af[m] = *(const bfx8*)(Ab + row*64 + ((ublk ^ (row & 7)) << 3));
            }
            #pragma unroll
            for (int n = 0; n < 4; ++n){
                int col = wn*64 + n*16 + r16;
                bfr[n] = *(const bfx8*)(Bb + col*64 + ((ublk ^ (col & 7)) << 3));
            }
            #pragma unroll
            for (int m = 0; m < 4; ++m)
                #pragma unroll
                for (int n = 0; n < 4; ++n)
                    acc[m][n] = __builtin_amdgcn_mfma_f32_16x16x32_bf16(
                                    af[m], bfr[n], acc[m][n], 0, 0, 0);
            if (doE){
                bfx8 be = *(const bfx8*)(wcatbT + (size_t)r16*KK + k0 + kk + ksub*8);
                #pragma unroll
                for (int m = 0; m < 4; ++m)
                    acc_e[m] = __builtin_amdgcn_mfma_f32_16x16x32_bf16(
                                    af[m], be, acc_e[m], 0, 0, 0);
            }
        }
        __syncthreads();
    }
    // epilogue: C/D layout col=lane&15, row=(lane>>4)*4+i ; store bf16, stride 512.
    // NNP is a multiple of 128 -> all rows in-bounds.
    int cr = ksub, cc = r16;
    #pragma unroll
    for (int m = 0; m < 4; ++m){
        #pragma unroll
        for (int i = 0; i < 4; ++i){
            int row = m0 + wm*64 + m*16 + cr*4 + i;
            #pragma unroll
            for (int n = 0; n < 4; ++n)
                C[(size_t)row*HD2 + n0 + wn*64 + n*16 + cc] = f2bf(acc[m][n][i]);
        }
    }
    if (doE){
        #pragma unroll
        for (int m = 0; m < 4; ++m){
            #pragma unroll
            for (int i = 0; i < 4; ++i){
                int row = m0 + wm*64 + m*16 + cr*4 + i;
                if (row < NN) eall[(size_t)row*16 + cc] = acc_e[m][i];
            }
        }
    }
}

// one wave per node, both relations; feature-per-lane (4 f32/lane).
// MINIMAL-VGPR simple loop + no-max softmax + epak f16 el stream + nt-store.
// Segment bounds: end = cur[rn] (post-scatter), beg = end - cnt[rn].
// Runs at the random-gather ceiling (~2.85 TB/s effective).
__global__ __launch_bounds__(256) void k_agg(const unsigned* __restrict__ cur,
                                             const unsigned* __restrict__ cnt,
                                             const int* __restrict__ esrc,
                                             const uint2* __restrict__ epak,
                                             const float* __restrict__ eall,
                                             const ushort* __restrict__ fsall,
                                             const float* __restrict__ bias,
                                             float* __restrict__ out){
    int w = threadIdx.x >> 6, lane = threadIdx.x & 63;
    int n = blockIdx.x*4 + w;
    int h = lane >> 4;
    float rx = 0.f, ry = 0.f, rz = 0.f, rw = 0.f;
    #pragma unroll
    for (int r = 0; r < RR; ++r){
        unsigned num = cnt[(size_t)r*NN + n];
        unsigned beg = cur[(size_t)r*NN + n] - num;   // cur = end after scatter
        float er = eall[(size_t)n*16 + r*8 + 4 + h];
        float den = 0.f;
        float ax = 0.f, ay = 0.f, az = 0.f, aw = 0.f;
        for (unsigned u = beg; u < beg + num; ++u){
            int s = esrc[u];
            uint2 ep = epak[u];
            unsigned wsel = (h & 2) ? ep.y : ep.x;
            ushort hv = (h & 1) ? (ushort)(wsel >> 16) : (ushort)wsel;
            __fp16 hf = *(__fp16*)&hv;
            float v = (float)hf + er;
            v = v > 0.f ? v : NEG_SLOPE*v;
            float p = __expf(v);
            ushort4 f = *(const ushort4*)(fsall + (size_t)s*HD2 + r*HD + lane*4);
            den += p;
            ax += p*bf2f(f.x); ay += p*bf2f(f.y);
            az += p*bf2f(f.z); aw += p*bf2f(f.w);
        }
        float inv = den > 0.f ? 1.f/den : 0.f;
        rx += ax*inv; ry += ay*inv;
        rz += az*inv; rw += aw*inv;
    }
    const float4 b0 = *(const float4*)(bias + lane*4);
    const float4 b1 = *(const float4*)(bias + HD + lane*4);
    f32x4 res;
    res[0] = rx + b0.x + b1.x; res[1] = ry + b0.y + b1.y;
    res[2] = rz + b0.z + b1.z; res[3] = rw + b0.w + b1.w;
    __builtin_nontemporal_store(res, (f32x4*)(out + (size_t)n*HD + lane*4));
}

extern "C" void kernel_launch(void* const* d_in, const int* in_sizes, int n_in,
                              void* d_out, int out_size, void* d_ws, size_t ws_size,
                              hipStream_t stream) {
    const float* x     = (const float*)d_in[0];
    const float* W_src = (const float*)d_in[1];
    const float* W_dst = (const float*)d_in[2];
    const float* al    = (const float*)d_in[3];
    const float* ar    = (const float*)d_in[4];
    const float* bias  = (const float*)d_in[5];
    const int*   sidx  = (const int*)d_in[6];
    const int*   didx  = (const int*)d_in[7];
    float* out = (float*)d_out;

    // workspace carve-up: 123,030,816 B total (below R14/R16's proven footprint)
    ushort*   fsall  = (ushort*)d_ws;                        // NNP*512 bf16
    ushort*   Wt     = fsall + (size_t)NNP*HD2;              // 512*256 bf16
    ushort*   wcatbT = Wt + (size_t)RR*KK*HD;                // 16*256 bf16
    float*    eall   = (float*)(wcatbT + 16*KK);             // N*16 f32
    unsigned* cnt    = (unsigned*)(eall + (size_t)NN*16);    // R*N
    unsigned* cursor = cnt + (size_t)RR*NN;                  // 8 (1 + pad)
    unsigned* cur    = cursor + 8;                           // R*N (start->end)
    int*      esrc   = (int*)(cur + (size_t)RR*NN);          // R*E ints
    uint2*    epak   = (uint2*)(esrc + (size_t)RR*EE);       // R*E uint2

    k_prep<<<(RR*KK*HD + 255)/256, 256, 0, stream>>>(W_src, W_dst, al, ar, Wt, wcatbT, cnt);
    k_gemm<<<MT*4, 256, 0, stream>>>(x, Wt, wcatbT, didx, cnt, fsall, eall);

    k_alloc<<<(RR*NN + 255)/256, 256, 0, stream>>>(cnt, cur, cursor);
    k_scatter<<<(RR*EE + 255)/256, 256, 0, stream>>>(sidx, didx, eall, cur, esrc, epak);

    k_agg<<<NN/4, 256, 0, stream>>>(cur, cnt, esrc, epak, eall, fsall, bias, out);
}